// Round 1
// 138.460 us; speedup vs baseline: 1.0574x; 1.0574x over previous
//
#include <hip/hip_runtime.h>

// DynamiConv via implicit-im2col f16 MFMA; single-barrier structure:
//   staging thread owns ONE halo position: loads its 32 channels (uniform voff +
//   per-channel SGPR base), computes sigma once, 9 gate tap-partials in regs,
//   writes f16 values + gpart to LDS. Then 1 barrier, then MFMA K-loop.
//   out[b,o,y,x] = gate[b,y,x]*(W.cols)[o] + bias[o];
//   gate = sum_tap gpart[tap][pos+off(tap)], gpart = dW[:,tap].sigma(v[:,pos])
// R1 change: A-pack (identical for all 4 waves, 18KB) no longer fetched from
//   global inside the MFMA loop (VGPR=40 proved no hoisting -> 18 L1/L2-latency
//   stalls per wave). Chunks 0..15 staged to LDS cooperatively (copy issued
//   first, lands under the staging phase's existing vmcnt+barrier); chunks
//   16..17 preloaded to 8 VGPRs. LDS total 40048 B -> 4 blocks/CU.
// x[8,32,256,256] f32, W[32,32,3,3], dW[1,32,3,3], bias[32] -> out[8,32,256,256] f32

typedef _Float16 half8 __attribute__((ext_vector_type(8)));
typedef float f32x16 __attribute__((ext_vector_type(16)));

#define BATCH 8
#define CIN 32
#define COUT 32
#define HH 256
#define WW 256
#define TW 32           // spatial tile width (one MFMA n-tile)
#define TH 4            // spatial tile height: 4 rows, 1 per wave, 256 thr
#define HTW 34
#define HTH 6
#define CSTR 40         // f16 per position (32 ch + 8 pad) = 80 B stride
#define NCHUNK 18       // K=288 as 18 chunks of 16: chunk q -> tap=q>>1, c-half=q&1
#define NLDSA 16        // A chunks staged in LDS; chunks 16,17 live in VGPRs
#define NPOS (HTH*HTW)  // 204 halo positions (<= 256 threads: one owner each)

// Apack = W in per-lane MFMA A order (o=lane&31, c=(q&1)*16+(lane>>5)*8+j, tap=q>>1).
// dwf[tap][c] = dW[c][tap] (288 f32, tap-major; wave-uniform reads at staging).
__global__ __launch_bounds__(256) void prep_pack(const float* __restrict__ w,
                                                 const float* __restrict__ dw,
                                                 _Float16* __restrict__ Apack,
                                                 float* __restrict__ dwf) {
  int t = blockIdx.x * 256 + threadIdx.x;
  if (t < 9216) {
    int q = t >> 9, lane = (t >> 3) & 63, j = t & 7;
    int tap = q >> 1, h = q & 1;
    int o = lane & 31, lh = lane >> 5;
    int c = h * 16 + lh * 8 + j;
    Apack[t] = (_Float16)w[o * 288 + c * 9 + tap];
  } else if (t < 9216 + 288) {
    int i = t - 9216;
    int tap = i >> 5, c = i & 31;
    dwf[i] = dw[c * 9 + tap];
  }
}

__global__ __launch_bounds__(256, 4) void dynconv(
    const float* __restrict__ x, const _Float16* __restrict__ Apack,
    const float* __restrict__ dwf, const float* __restrict__ bias,
    float* __restrict__ out) {
  __shared__ __align__(16) _Float16 lvA[NLDSA * 512];  // 16384 B: A chunks 0..15
  __shared__ __align__(16) _Float16 lv[NPOS * CSTR];   // 16320 B f16 values
  __shared__ float gpart[9 * NPOS];                    // 7344 B gate tap-partials

  // XCD-batch swizzle: XCD k handles batch k; halo re-reads stay in its L2.
  const int bid0 = blockIdx.x;              // grid = 4096
  const int bb = bid0 & 7, idx = bid0 >> 3;
  const int xt = idx & 7, yt = idx >> 3;    // yt < 64
  const int x0 = xt * TW, y0 = yt * TH;
  const int tid = threadIdx.x;
  const int lane = tid & 63;

  // ---- A-pack register chunks (16,17): issued first, consumed last ----
  const half8 a16 = *(const half8*)(Apack + ((16 * 64 + lane) << 3));
  const half8 a17 = *(const half8*)(Apack + ((17 * 64 + lane) << 3));

  // ---- A-pack chunks 0..15 -> LDS: 4x dwordx4 per thread, lane-linear.
  // Loads issued before the x staging loads; ds_writes below wait only on
  // these (compiler emits counted vmcnt), x loads stay in flight.
  half8 acopy[4];
#pragma unroll
  for (int k = 0; k < 4; ++k)
    acopy[k] = *(const half8*)(Apack + ((k * 256 + tid) << 3));

  // ---- staging: one owner thread per halo position, single pass ----
  const bool owner = tid < NPOS;
  float v[CIN];
  if (owner) {
    const int yy = tid / HTW, xx = tid - (tid / HTW) * HTW;
    const int gy = y0 + yy - 1, gx = x0 + xx - 1;
    const int voff = (gy << 8) + gx;        // uniform across c -> saddr-form loads
    if ((unsigned)gy < 256u && (unsigned)gx < 256u) {
#pragma unroll
      for (int c = 0; c < CIN; ++c)
        v[c] = x[(((size_t)(bb * CIN + c)) << 16) + voff];  // 32-deep MLP
    } else {
#pragma unroll
      for (int c = 0; c < CIN; ++c) v[c] = 0.f;
    }
  }

  // A-pack LDS writes (waits on acopy loads only; x loads remain outstanding)
#pragma unroll
  for (int k = 0; k < 4; ++k)
    *(half8*)(lvA + ((k * 256 + tid) << 3)) = acopy[k];

  if (owner) {
    float p[9];
#pragma unroll
    for (int tap = 0; tap < 9; ++tap) p[tap] = 0.f;
    _Float16 hv[CIN];
#pragma unroll
    for (int c = 0; c < CIN; ++c) {
      const float s = __builtin_amdgcn_rcpf(1.f + __expf(-v[c]));
#pragma unroll
      for (int tap = 0; tap < 9; ++tap)
        p[tap] += dwf[tap * 32 + c] * s;    // dwf uniform -> SGPR operand
      hv[c] = (_Float16)v[c];
    }
#pragma unroll
    for (int u = 0; u < 4; ++u)
      *(half8*)(lv + tid * CSTR + u * 8) = *(const half8*)(hv + u * 8);
#pragma unroll
    for (int tap = 0; tap < 9; ++tap)
      gpart[tap * NPOS + tid] = p[tap];     // exclusive owner: plain ds_write
  }
  __syncthreads();

  // ---- compute: wave w8 owns tile row y0+w8; 18 chunks, 1 MFMA each ----
  const int w8 = tid >> 6;                  // w8 in 0..3
  const int ln = lane & 31, lh = lane >> 5;

  float gate = 0.f;
#pragma unroll
  for (int ki = 0; ki < 3; ++ki)
#pragma unroll
    for (int kj = 0; kj < 3; ++kj)
      gate += gpart[(ki * 3 + kj) * NPOS + (w8 + ki) * HTW + ln + kj];

  f32x16 acc;
#pragma unroll
  for (int i = 0; i < 16; ++i) acc[i] = 0.f;

#pragma unroll
  for (int q = 0; q < NCHUNK; ++q) {
    const int tap = q >> 1, h = q & 1;
    const int ki = tap / 3, kj = tap - ki * 3;
    const half8 a = (q < NLDSA)
                        ? *(const half8*)(lvA + ((q * 64 + lane) << 3))  // LDS, lane-linear
                        : (q == 16 ? a16 : a17);                         // VGPR-resident
    const int off = ((w8 + ki) * HTW + ln + kj) * CSTR + h * 16 + lh * 8;
    const half8 bv = *(const half8*)(lv + off);   // ds_read_b128
    acc = __builtin_amdgcn_mfma_f32_32x32x16_f16(a, bv, acc, 0, 0, 0);
  }

  // ---- epilogue: D layout col=lane&31, row=(reg&3)+8*(reg>>2)+4*(lane>>5) ----
  const int voff_out = ((y0 + w8) << 8) + x0 + ln;
#pragma unroll
  for (int reg = 0; reg < 16; ++reg) {
    const int o = (reg & 3) + 8 * (reg >> 2) + 4 * lh;
    out[(((size_t)(bb * COUT + o)) << 16) + voff_out] = acc[reg] * gate + bias[o];
  }
}

extern "C" void kernel_launch(void* const* d_in, const int* in_sizes, int n_in,
                              void* d_out, int out_size, void* d_ws, size_t ws_size,
                              hipStream_t stream) {
  const float* x    = (const float*)d_in[0];
  const float* wgt  = (const float*)d_in[1];
  const float* dw   = (const float*)d_in[2];
  const float* bias = (const float*)d_in[3];
  float* out = (float*)d_out;

  _Float16* Apack = (_Float16*)d_ws;                 // 9216 f16 = 18432 B
  float* dwf      = (float*)((char*)d_ws + 18432);   // 288 f32

  prep_pack<<<(9216 + 288 + 255) / 256, 256, 0, stream>>>(wgt, dw, Apack, dwf);
  dynconv<<<BATCH * (HH / TH) * (WW / TW), 256, 0, stream>>>(x, Apack, dwf, bias, out);
}

// Round 2
// 138.192 us; speedup vs baseline: 1.0595x; 1.0019x over previous
//
#include <hip/hip_runtime.h>

// DynamiConv via implicit-im2col f16 MFMA; single-barrier structure:
//   staging thread owns ONE halo position: loads its 32 channels (uniform voff +
//   per-channel SGPR base), computes sigma once, 9 gate tap-partials in regs,
//   writes f16 values + gpart to LDS. Then 1 barrier, then MFMA K-loop.
//   out[b,o,y,x] = gate[b,y,x]*(W.cols)[o] + bias[o];
//   gate = sum_tap gpart[tap][pos+off(tap)], gpart = dW[:,tap].sigma(v[:,pos])
// R1: A-pack staged to LDS (chunks in regs for the tail) -> removed 18 in-loop
//   global A fetches; -7us, but LDS 40.4KB capped residency at 4 blocks/CU.
// R2: (a) gate via v_dot2_f32_f16 on f16x2-packed dW (144 dot2 vs 288 fmac,
//   half the s_load traffic; dwf2 tap-minor so the 9-tap loop is one
//   contiguous 36B scalar batch). (b) LDS diet: gpart f16 (3672B), A-pack
//   12 chunks LDS + 6 chunks VGPR -> LDS 32280B -> 5 blocks/CU.
//   __launch_bounds__(256,5) caps VGPR at 102 (est ~90).
// x[8,32,256,256] f32, W[32,32,3,3], dW[1,32,3,3], bias[32] -> out[8,32,256,256] f32

typedef _Float16 half8 __attribute__((ext_vector_type(8)));
typedef _Float16 half2 __attribute__((ext_vector_type(2)));
typedef float f32x16 __attribute__((ext_vector_type(16)));

#define BATCH 8
#define CIN 32
#define COUT 32
#define HH 256
#define WW 256
#define TW 32           // spatial tile width (one MFMA n-tile)
#define TH 4            // spatial tile height: 4 rows, 1 per wave, 256 thr
#define HTW 34
#define HTH 6
#define CSTR 40         // f16 per position (32 ch + 8 pad) = 80 B stride
#define NCHUNK 18       // K=288 as 18 chunks of 16: chunk q -> tap=q>>1, c-half=q&1
#define NLDSA 12        // A chunks staged in LDS; chunks 12..17 live in VGPRs
#define NREGA (NCHUNK - NLDSA)
#define NPOS (HTH*HTW)  // 204 halo positions (<= 256 threads: one owner each)

// Apack = W in per-lane MFMA A order (o=lane&31, c=(q&1)*16+(lane>>5)*8+j, tap=q>>1).
// dwf2[cp][tap] = (dW[2cp][tap], dW[2cp+1][tap]) f16x2 — tap-minor so the
// staging 9-tap loop reads 36 contiguous bytes (one s_load_dwordx8 batch).
__global__ __launch_bounds__(256) void prep_pack(const float* __restrict__ w,
                                                 const float* __restrict__ dw,
                                                 _Float16* __restrict__ Apack,
                                                 half2* __restrict__ dwf2) {
  int t = blockIdx.x * 256 + threadIdx.x;
  if (t < 9216) {
    int q = t >> 9, lane = (t >> 3) & 63, j = t & 7;
    int tap = q >> 1, h = q & 1;
    int o = lane & 31, lh = lane >> 5;
    int c = h * 16 + lh * 8 + j;
    Apack[t] = (_Float16)w[o * 288 + c * 9 + tap];
  } else if (t < 9216 + 144) {
    int i = t - 9216;          // i = cp*9 + tap
    int cp = i / 9, tap = i - cp * 9;
    half2 d;
    d.x = (_Float16)dw[(2 * cp) * 9 + tap];
    d.y = (_Float16)dw[(2 * cp + 1) * 9 + tap];
    dwf2[i] = d;
  }
}

__global__ __launch_bounds__(256, 5) void dynconv(
    const float* __restrict__ x, const _Float16* __restrict__ Apack,
    const half2* __restrict__ dwf2, const float* __restrict__ bias,
    float* __restrict__ out) {
  __shared__ __align__(16) _Float16 lvA[NLDSA * 512];  // 12288 B: A chunks 0..11
  __shared__ __align__(16) _Float16 lv[NPOS * CSTR];   // 16320 B f16 values
  __shared__ _Float16 gpart[9 * NPOS];                 // 3672 B gate tap-partials

  // XCD-batch swizzle: XCD k handles batch k; halo re-reads stay in its L2.
  const int bid0 = blockIdx.x;              // grid = 4096
  const int bb = bid0 & 7, idx = bid0 >> 3;
  const int xt = idx & 7, yt = idx >> 3;    // yt < 64
  const int x0 = xt * TW, y0 = yt * TH;
  const int tid = threadIdx.x;
  const int lane = tid & 63;

  // ---- A-pack register chunks 12..17: issued first, consumed last ----
  half8 areg[NREGA];
#pragma unroll
  for (int r = 0; r < NREGA; ++r)
    areg[r] = *(const half8*)(Apack + (((NLDSA + r) * 64 + lane) << 3));

  // ---- A-pack chunks 0..11 -> LDS: 3x dwordx4 per thread, lane-linear.
  // Loads issued before the x staging loads; the ds_writes below wait only
  // on these (counted vmcnt), x loads stay in flight.
  half8 acopy[3];
#pragma unroll
  for (int k = 0; k < 3; ++k)
    acopy[k] = *(const half8*)(Apack + ((k * 256 + tid) << 3));

  // ---- staging: one owner thread per halo position, single pass ----
  const bool owner = tid < NPOS;
  float v[CIN];
  if (owner) {
    const int yy = tid / HTW, xx = tid - (tid / HTW) * HTW;
    const int gy = y0 + yy - 1, gx = x0 + xx - 1;
    const int voff = (gy << 8) + gx;        // uniform across c -> saddr-form loads
    if ((unsigned)gy < 256u && (unsigned)gx < 256u) {
#pragma unroll
      for (int c = 0; c < CIN; ++c)
        v[c] = x[(((size_t)(bb * CIN + c)) << 16) + voff];  // 32-deep MLP
    } else {
#pragma unroll
      for (int c = 0; c < CIN; ++c) v[c] = 0.f;
    }
  }

  // A-pack LDS writes (waits on acopy loads only; x loads remain outstanding)
#pragma unroll
  for (int k = 0; k < 3; ++k)
    *(half8*)(lvA + ((k * 256 + tid) << 3)) = acopy[k];

  if (owner) {
    float p[9];
#pragma unroll
    for (int tap = 0; tap < 9; ++tap) p[tap] = 0.f;
    _Float16 hv[CIN];
#pragma unroll
    for (int cp = 0; cp < CIN / 2; ++cp) {
      const float v0 = v[2 * cp], v1 = v[2 * cp + 1];
      const float s0 = __builtin_amdgcn_rcpf(1.f + __expf(-v0));
      const float s1 = __builtin_amdgcn_rcpf(1.f + __expf(-v1));
      half2 s2;
      s2.x = (_Float16)s0;
      s2.y = (_Float16)s1;
      hv[2 * cp] = (_Float16)v0;
      hv[2 * cp + 1] = (_Float16)v1;
#pragma unroll
      for (int tap = 0; tap < 9; ++tap) {
        const half2 d2 = dwf2[cp * 9 + tap];   // uniform -> SGPR operand
#if __has_builtin(__builtin_amdgcn_fdot2)
        p[tap] = __builtin_amdgcn_fdot2(s2, d2, p[tap], false);
#else
        p[tap] += (float)s2.x * (float)d2.x + (float)s2.y * (float)d2.y;
#endif
      }
    }
#pragma unroll
    for (int u = 0; u < 4; ++u)
      *(half8*)(lv + tid * CSTR + u * 8) = *(const half8*)(hv + u * 8);
#pragma unroll
    for (int tap = 0; tap < 9; ++tap)
      gpart[tap * NPOS + tid] = (_Float16)p[tap];  // exclusive owner: plain ds_write
  }
  __syncthreads();

  // ---- compute: wave w8 owns tile row y0+w8; 18 chunks, 1 MFMA each ----
  const int w8 = tid >> 6;                  // w8 in 0..3
  const int ln = lane & 31, lh = lane >> 5;

  float gate = 0.f;
#pragma unroll
  for (int ki = 0; ki < 3; ++ki)
#pragma unroll
    for (int kj = 0; kj < 3; ++kj)
      gate += (float)gpart[(ki * 3 + kj) * NPOS + (w8 + ki) * HTW + ln + kj];

  f32x16 acc;
#pragma unroll
  for (int i = 0; i < 16; ++i) acc[i] = 0.f;

#pragma unroll
  for (int q = 0; q < NCHUNK; ++q) {
    const int tap = q >> 1, h = q & 1;
    const int ki = tap / 3, kj = tap - ki * 3;
    const half8 a = (q < NLDSA)
                        ? *(const half8*)(lvA + ((q * 64 + lane) << 3))  // LDS, lane-linear
                        : areg[q - NLDSA];                               // VGPR-resident
    const int off = ((w8 + ki) * HTW + ln + kj) * CSTR + h * 16 + lh * 8;
    const half8 bv = *(const half8*)(lv + off);   // ds_read_b128
    acc = __builtin_amdgcn_mfma_f32_32x32x16_f16(a, bv, acc, 0, 0, 0);
  }

  // ---- epilogue: D layout col=lane&31, row=(reg&3)+8*(reg>>2)+4*(lane>>5) ----
  const int voff_out = ((y0 + w8) << 8) + x0 + ln;
#pragma unroll
  for (int reg = 0; reg < 16; ++reg) {
    const int o = (reg & 3) + 8 * (reg >> 2) + 4 * lh;
    out[(((size_t)(bb * COUT + o)) << 16) + voff_out] = acc[reg] * gate + bias[o];
  }
}

extern "C" void kernel_launch(void* const* d_in, const int* in_sizes, int n_in,
                              void* d_out, int out_size, void* d_ws, size_t ws_size,
                              hipStream_t stream) {
  const float* x    = (const float*)d_in[0];
  const float* wgt  = (const float*)d_in[1];
  const float* dw   = (const float*)d_in[2];
  const float* bias = (const float*)d_in[3];
  float* out = (float*)d_out;

  _Float16* Apack = (_Float16*)d_ws;                  // 9216 f16 = 18432 B
  half2* dwf2     = (half2*)((char*)d_ws + 18432);    // 144 half2 = 576 B

  prep_pack<<<(9216 + 144 + 255) / 256, 256, 0, stream>>>(wgt, dw, Apack, dwf2);
  dynconv<<<BATCH * (HH / TH) * (WW / TW), 256, 0, stream>>>(x, Apack, dwf2, bias, out);
}

// Round 3
// 133.358 us; speedup vs baseline: 1.0979x; 1.0362x over previous
//
#include <hip/hip_runtime.h>

// DynamiConv via implicit-im2col f16 MFMA; single-barrier structure:
//   staging thread owns ONE halo position: loads its 32 channels (uniform voff +
//   per-channel SGPR base), computes sigma once, 9 gate tap-partials in regs,
//   writes f16 values + gpart to LDS. Then 1 barrier, then MFMA K-loop.
//   out[b,o,y,x] = gate[b,y,x]*(W.cols)[o] + bias[o];
//   gate = sum_tap gpart[tap][pos+off(tap)], gpart = dW[:,tap].sigma(v[:,pos])
// R1: A-pack staged to LDS -> removed 18 in-loop global A fetches (-7.5us).
// R2: gate via v_dot2_f32_f16 on packed dW; gpart f16; LDS diet (-3us).
// R3: TH=8 tile (512 thr, 8 waves). Ledger shows dur tracks per-block
//   critical path (staging) with effective concurrency ~const; staging cost
//   scales with HALO (340) while output scales with INTERIOR (256):
//   redundancy 1.59x -> 1.33x. Per-output sigma VALU, x-load issue and
//   re-fetch all -16%. LDS 45608 B -> 3 blocks/CU = 24 waves/CU.
// x[8,32,256,256] f32, W[32,32,3,3], dW[1,32,3,3], bias[32] -> out[8,32,256,256] f32

typedef _Float16 half8 __attribute__((ext_vector_type(8)));
typedef _Float16 half2 __attribute__((ext_vector_type(2)));
typedef float f32x16 __attribute__((ext_vector_type(16)));

#define BATCH 8
#define CIN 32
#define COUT 32
#define HH 256
#define WW 256
#define TW 32           // spatial tile width (one MFMA n-tile)
#define TH 8            // spatial tile height: 8 rows, 1 per wave, 512 thr
#define HTW 34
#define HTH 10
#define CSTR 40         // f16 per position (32 ch + 8 pad) = 80 B stride
#define NCHUNK 18       // K=288 as 18 chunks of 16: chunk q -> tap=q>>1, c-half=q&1
#define NLDSA 12        // A chunks staged in LDS; chunks 12..17 live in VGPRs
#define NREGA (NCHUNK - NLDSA)
#define NPOS (HTH*HTW)  // 340 halo positions (<= 512 threads: one owner each)

// Apack = W in per-lane MFMA A order (o=lane&31, c=(q&1)*16+(lane>>5)*8+j, tap=q>>1).
// dwf2[cp][tap] = (dW[2cp][tap], dW[2cp+1][tap]) f16x2 — tap-minor so the
// staging 9-tap loop reads 36 contiguous bytes (one s_load batch).
__global__ __launch_bounds__(256) void prep_pack(const float* __restrict__ w,
                                                 const float* __restrict__ dw,
                                                 _Float16* __restrict__ Apack,
                                                 half2* __restrict__ dwf2) {
  int t = blockIdx.x * 256 + threadIdx.x;
  if (t < 9216) {
    int q = t >> 9, lane = (t >> 3) & 63, j = t & 7;
    int tap = q >> 1, h = q & 1;
    int o = lane & 31, lh = lane >> 5;
    int c = h * 16 + lh * 8 + j;
    Apack[t] = (_Float16)w[o * 288 + c * 9 + tap];
  } else if (t < 9216 + 144) {
    int i = t - 9216;          // i = cp*9 + tap
    int cp = i / 9, tap = i - cp * 9;
    half2 d;
    d.x = (_Float16)dw[(2 * cp) * 9 + tap];
    d.y = (_Float16)dw[(2 * cp + 1) * 9 + tap];
    dwf2[i] = d;
  }
}

__global__ __launch_bounds__(512, 6) void dynconv(
    const float* __restrict__ x, const _Float16* __restrict__ Apack,
    const half2* __restrict__ dwf2, const float* __restrict__ bias,
    float* __restrict__ out) {
  __shared__ __align__(16) _Float16 lvA[NLDSA * 512];  // 12288 B: A chunks 0..11
  __shared__ __align__(16) _Float16 lv[NPOS * CSTR];   // 27200 B f16 values
  __shared__ _Float16 gpart[9 * NPOS];                 // 6120 B gate tap-partials

  // XCD-batch swizzle: XCD k handles batch k; halo re-reads stay in its L2.
  const int bid0 = blockIdx.x;              // grid = 2048
  const int bb = bid0 & 7, idx = bid0 >> 3;
  const int xt = idx & 7, yt = idx >> 3;    // yt < 32
  const int x0 = xt * TW, y0 = yt * TH;
  const int tid = threadIdx.x;
  const int lane = tid & 63;

  // ---- A-pack register chunks 12..17: issued first, consumed last ----
  half8 areg[NREGA];
#pragma unroll
  for (int r = 0; r < NREGA; ++r)
    areg[r] = *(const half8*)(Apack + (((NLDSA + r) * 64 + lane) << 3));

  // ---- A-pack chunks 0..11 -> LDS: 768 half8 units over 512 threads.
  // Loads issued before the x staging loads; the ds_writes below wait only
  // on these (counted vmcnt), x loads stay in flight.
  half8 acopy0 = *(const half8*)(Apack + (tid << 3));
  half8 acopy1;
  if (tid < NLDSA * 64 - 512)
    acopy1 = *(const half8*)(Apack + ((512 + tid) << 3));

  // ---- staging: one owner thread per halo position, single pass ----
  const bool owner = tid < NPOS;
  float v[CIN];
  if (owner) {
    const int yy = tid / HTW, xx = tid - (tid / HTW) * HTW;
    const int gy = y0 + yy - 1, gx = x0 + xx - 1;
    const int voff = (gy << 8) + gx;        // uniform across c -> saddr-form loads
    if ((unsigned)gy < 256u && (unsigned)gx < 256u) {
#pragma unroll
      for (int c = 0; c < CIN; ++c)
        v[c] = x[(((size_t)(bb * CIN + c)) << 16) + voff];  // 32-deep MLP
    } else {
#pragma unroll
      for (int c = 0; c < CIN; ++c) v[c] = 0.f;
    }
  }

  // A-pack LDS writes (waits on acopy loads only; x loads remain outstanding)
  *(half8*)(lvA + (tid << 3)) = acopy0;
  if (tid < NLDSA * 64 - 512)
    *(half8*)(lvA + ((512 + tid) << 3)) = acopy1;

  if (owner) {
    float p[9];
#pragma unroll
    for (int tap = 0; tap < 9; ++tap) p[tap] = 0.f;
    _Float16 hv[CIN];
#pragma unroll
    for (int cp = 0; cp < CIN / 2; ++cp) {
      const float v0 = v[2 * cp], v1 = v[2 * cp + 1];
      const float s0 = __builtin_amdgcn_rcpf(1.f + __expf(-v0));
      const float s1 = __builtin_amdgcn_rcpf(1.f + __expf(-v1));
      half2 s2;
      s2.x = (_Float16)s0;
      s2.y = (_Float16)s1;
      hv[2 * cp] = (_Float16)v0;
      hv[2 * cp + 1] = (_Float16)v1;
#pragma unroll
      for (int tap = 0; tap < 9; ++tap) {
        const half2 d2 = dwf2[cp * 9 + tap];   // uniform -> SGPR operand
#if __has_builtin(__builtin_amdgcn_fdot2)
        p[tap] = __builtin_amdgcn_fdot2(s2, d2, p[tap], false);
#else
        p[tap] += (float)s2.x * (float)d2.x + (float)s2.y * (float)d2.y;
#endif
      }
    }
#pragma unroll
    for (int u = 0; u < 4; ++u)
      *(half8*)(lv + tid * CSTR + u * 8) = *(const half8*)(hv + u * 8);
#pragma unroll
    for (int tap = 0; tap < 9; ++tap)
      gpart[tap * NPOS + tid] = (_Float16)p[tap];  // exclusive owner: plain ds_write
  }
  __syncthreads();

  // ---- compute: wave w8 owns tile row y0+w8; 18 chunks, 1 MFMA each ----
  const int w8 = tid >> 6;                  // w8 in 0..7
  const int ln = lane & 31, lh = lane >> 5;

  float gate = 0.f;
#pragma unroll
  for (int ki = 0; ki < 3; ++ki)
#pragma unroll
    for (int kj = 0; kj < 3; ++kj)
      gate += (float)gpart[(ki * 3 + kj) * NPOS + (w8 + ki) * HTW + ln + kj];

  f32x16 acc;
#pragma unroll
  for (int i = 0; i < 16; ++i) acc[i] = 0.f;

#pragma unroll
  for (int q = 0; q < NCHUNK; ++q) {
    const int tap = q >> 1, h = q & 1;
    const int ki = tap / 3, kj = tap - ki * 3;
    const half8 a = (q < NLDSA)
                        ? *(const half8*)(lvA + ((q * 64 + lane) << 3))  // LDS, lane-linear
                        : areg[q - NLDSA];                               // VGPR-resident
    const int off = ((w8 + ki) * HTW + ln + kj) * CSTR + h * 16 + lh * 8;
    const half8 bv = *(const half8*)(lv + off);   // ds_read_b128
    acc = __builtin_amdgcn_mfma_f32_32x32x16_f16(a, bv, acc, 0, 0, 0);
  }

  // ---- epilogue: D layout col=lane&31, row=(reg&3)+8*(reg>>2)+4*(lane>>5) ----
  const int voff_out = ((y0 + w8) << 8) + x0 + ln;
#pragma unroll
  for (int reg = 0; reg < 16; ++reg) {
    const int o = (reg & 3) + 8 * (reg >> 2) + 4 * lh;
    out[(((size_t)(bb * COUT + o)) << 16) + voff_out] = acc[reg] * gate + bias[o];
  }
}

extern "C" void kernel_launch(void* const* d_in, const int* in_sizes, int n_in,
                              void* d_out, int out_size, void* d_ws, size_t ws_size,
                              hipStream_t stream) {
  const float* x    = (const float*)d_in[0];
  const float* wgt  = (const float*)d_in[1];
  const float* dw   = (const float*)d_in[2];
  const float* bias = (const float*)d_in[3];
  float* out = (float*)d_out;

  _Float16* Apack = (_Float16*)d_ws;                  // 9216 f16 = 18432 B
  half2* dwf2     = (half2*)((char*)d_ws + 18432);    // 144 half2 = 576 B

  prep_pack<<<(9216 + 144 + 255) / 256, 256, 0, stream>>>(wgt, dw, Apack, dwf2);
  dynconv<<<BATCH * (HH / TH) * (WW / TW), 512, 0, stream>>>(x, Apack, dwf2, bias, out);
}